// Round 1
// baseline (12557.232 us; speedup 1.0000x reference)
//
#include <hip/hip_runtime.h>

#define NN 50000
#define NE 800000
#define EPSV 1e-5f

// ---------------- degree / coef ----------------
__global__ void k_init_deg(float* __restrict__ deg){
  int i = blockIdx.x*256 + threadIdx.x;
  if (i < NN) deg[i] = 1.0f;
}

__global__ void k_deg_accum(const int* __restrict__ ei, const float* __restrict__ ea,
                            float* __restrict__ deg){
  int e = blockIdx.x*256 + threadIdx.x;
  if (e < NE){
    int d = ei[NE + e];
    atomicAdd(&deg[d], ea[3*e+2]);
  }
}

__global__ void k_fin_deg(const float* __restrict__ deg, float* __restrict__ dinv,
                          float* __restrict__ dinv2){
  int i = blockIdx.x*256 + threadIdx.x;
  if (i < NN){ float r = rsqrtf(deg[i]); dinv[i] = r; dinv2[i] = r*r; }
}

__global__ void k_coef(const int* __restrict__ ei, const float* __restrict__ ea,
                       const float* __restrict__ dinv, float* __restrict__ coef){
  int e = blockIdx.x*256 + threadIdx.x;
  if (e < NE){
    int s = ei[e], d = ei[NE+e];
    coef[e] = dinv[s]*ea[3*e+2]*dinv[d];
  }
}

// ---------------- aggregation: h_t = dinv2*h_in + sum_e coef*h_in[src] ----------------
__global__ void k_seed(const float* __restrict__ hin, const float* __restrict__ dinv2,
                       float* __restrict__ ht, int K){
  int idx = blockIdx.x*256 + threadIdx.x;
  if (idx < NN*K){
    int i = idx / K;
    ht[idx] = dinv2[i]*hin[idx];
  }
}

__global__ void k_scatter(const int* __restrict__ ei, const float* __restrict__ coef,
                          const float* __restrict__ hin, float* __restrict__ ht, int K){
  int e = blockIdx.x*4 + (threadIdx.x >> 6);
  int lane = threadIdx.x & 63;
  int s = ei[e], d = ei[NE+e];
  float c = coef[e];
  const float* hs = hin + (size_t)s*K;
  float* hd = ht + (size_t)d*K;
  for (int f = lane; f < K; f += 64)
    atomicAdd(&hd[f], c*hs[f]);
}

// ---------------- fp32 tiled GEMM: C = A(NNxK) @ W(KxM) + bias ----------------
__global__ __launch_bounds__(256) void k_gemm_bias(
    const float* __restrict__ A, const float* __restrict__ W,
    const float* __restrict__ bias, float* __restrict__ C, int K, int M){
  const int BM=128, BN=128, BK=16;
  __shared__ float As[BK][BM+4];
  __shared__ float Bs[BK][BN];
  int tid = threadIdx.x;
  int tx = tid & 15, ty = tid >> 4;
  int row0 = blockIdx.y * BM;
  int col0 = blockIdx.x * BN;
  float acc[8][8] = {};
  for (int k0 = 0; k0 < K; k0 += BK){
    #pragma unroll
    for (int l = 0; l < 8; ++l){
      int i = tid + l*256;
      int m = i >> 4, k = i & 15;
      int r = row0 + m;
      As[k][m] = (r < NN) ? A[(size_t)r*K + k0 + k] : 0.f;
    }
    #pragma unroll
    for (int l = 0; l < 8; ++l){
      int i = tid + l*256;
      int k = i >> 7, n = i & 127;
      int c = col0 + n;
      Bs[k][n] = (c < M) ? W[(size_t)(k0+k)*M + c] : 0.f;
    }
    __syncthreads();
    #pragma unroll
    for (int k = 0; k < BK; ++k){
      float a[8], b[8];
      #pragma unroll
      for (int i = 0; i < 8; ++i) a[i] = As[k][ty*8+i];
      #pragma unroll
      for (int j = 0; j < 8; ++j) b[j] = Bs[k][tx*8+j];
      #pragma unroll
      for (int i = 0; i < 8; ++i)
        #pragma unroll
        for (int j = 0; j < 8; ++j) acc[i][j] += a[i]*b[j];
    }
    __syncthreads();
  }
  #pragma unroll
  for (int i = 0; i < 8; ++i){
    int r = row0 + ty*8 + i;
    if (r >= NN) continue;
    #pragma unroll
    for (int j = 0; j < 8; ++j){
      int c = col0 + tx*8 + j;
      if (c < M) C[(size_t)r*M + c] = acc[i][j] + bias[c];
    }
  }
}

// ---------------- batchnorm ----------------
__global__ void k_bn_stats(const float* __restrict__ h, float* __restrict__ s1,
                           float* __restrict__ s2, int H){
  int c = blockIdx.x*blockDim.x + threadIdx.x;
  if (c >= H) return;
  int nch = gridDim.y;
  int rows_per = (NN + nch - 1)/nch;
  int r0 = blockIdx.y*rows_per;
  int r1 = r0 + rows_per; if (r1 > NN) r1 = NN;
  float a = 0.f, b = 0.f;
  for (int r = r0; r < r1; ++r){
    float v = h[(size_t)r*H + c];
    a += v; b += v*v;
  }
  atomicAdd(&s1[c], a);
  atomicAdd(&s2[c], b);
}

__global__ void k_bn_apply(float* __restrict__ h, const float* __restrict__ s1,
                           const float* __restrict__ s2, const float* __restrict__ g,
                           const float* __restrict__ be, int H){
  int idx = blockIdx.x*256 + threadIdx.x;
  if (idx >= NN*H) return;
  int c = idx % H;
  float m = s1[c] * (1.0f/NN);
  float v = s2[c] * (1.0f/NN) - m*m;
  float val = (h[idx]-m)*rsqrtf(v+EPSV)*g[c] + be[c];
  h[idx] = val > 0.f ? val : 0.f;
}

extern "C" void kernel_launch(void* const* d_in, const int* in_sizes, int n_in,
                              void* d_out, int out_size, void* d_ws, size_t ws_size,
                              hipStream_t stream){
  const float* x   = (const float*)d_in[0];
  const int*   ei  = (const int*)d_in[1];
  const float* ea  = (const float*)d_in[2];
  const float* W1  = (const float*)d_in[4];
  const float* b1  = (const float*)d_in[5];
  const float* g1  = (const float*)d_in[6];
  const float* be1 = (const float*)d_in[7];
  const float* W2  = (const float*)d_in[8];
  const float* b2  = (const float*)d_in[9];
  const float* g2  = (const float*)d_in[10];
  const float* be2 = (const float*)d_in[11];
  const float* W3  = (const float*)d_in[12];
  const float* b3  = (const float*)d_in[13];
  float* out = (float*)d_out;

  // workspace layout
  char* w = (char*)d_ws;
  float* deg   = (float*)w; w += (size_t)NN*4;
  float* dinv  = (float*)w; w += (size_t)NN*4;
  float* dinv2 = (float*)w; w += (size_t)NN*4;
  float* coef  = (float*)w; w += (size_t)NE*4;
  float* s1    = (float*)w; w += 1024*4;
  float* s2    = (float*)w; w += 1024*4;
  float* agg   = (float*)w; w += (size_t)NN*1024*4;   // 204.8 MB

  // stage intermediates inside d_out (dead before final GEMM rewrites it)
  float* h1 = out;                       // NN*512
  float* h2 = out + (size_t)NN*512;      // NN*1024

  const int T = 256;
  int gN = (NN+T-1)/T, gE = (NE+T-1)/T;

  k_init_deg<<<gN,T,0,stream>>>(deg);
  k_deg_accum<<<gE,T,0,stream>>>(ei, ea, deg);
  k_fin_deg<<<gN,T,0,stream>>>(deg, dinv, dinv2);
  k_coef<<<gE,T,0,stream>>>(ei, ea, dinv, coef);

  // ----- layer 1: agg over x (K=256), GEMM -> h1 (M=512), BN+ReLU -----
  k_seed<<<(NN*256+T-1)/T,T,0,stream>>>(x, dinv2, agg, 256);
  k_scatter<<<NE/4,T,0,stream>>>(ei, coef, x, agg, 256);
  { dim3 grid((512+127)/128, (NN+127)/128);
    k_gemm_bias<<<grid,T,0,stream>>>(agg, W1, b1, h1, 256, 512); }
  hipMemsetAsync(s1, 0, 2*1024*sizeof(float), stream);
  { dim3 grid(512/256, 128); k_bn_stats<<<grid,T,0,stream>>>(h1, s1, s2, 512); }
  k_bn_apply<<<(NN*512+T-1)/T,T,0,stream>>>(h1, s1, s2, g1, be1, 512);

  // ----- layer 2: agg over h1 (K=512), GEMM -> h2 (M=1024), BN+ReLU -----
  k_seed<<<(NN*512+T-1)/T,T,0,stream>>>(h1, dinv2, agg, 512);
  k_scatter<<<NE/4,T,0,stream>>>(ei, coef, h1, agg, 512);
  { dim3 grid((1024+127)/128, (NN+127)/128);
    k_gemm_bias<<<grid,T,0,stream>>>(agg, W2, b2, h2, 512, 1024); }
  hipMemsetAsync(s1, 0, 2*1024*sizeof(float), stream);
  { dim3 grid(1024/256, 128); k_bn_stats<<<grid,T,0,stream>>>(h2, s1, s2, 1024); }
  k_bn_apply<<<(NN*1024+T-1)/T,T,0,stream>>>(h2, s1, s2, g2, be2, 1024);

  // ----- layer 3: agg over h2 (K=1024), GEMM -> out (M=3000) -----
  k_seed<<<(NN*1024+T-1)/T,T,0,stream>>>(h2, dinv2, agg, 1024);
  k_scatter<<<NE/4,T,0,stream>>>(ei, coef, h2, agg, 1024);
  { dim3 grid((3000+127)/128, (NN+127)/128);
    k_gemm_bias<<<grid,T,0,stream>>>(agg, W3, b3, out, 1024, 3000); }
}

// Round 2
// 3472.532 us; speedup vs baseline: 3.6162x; 3.6162x over previous
//
#include <hip/hip_runtime.h>

#define NN 50000
#define NE 800000
#define EPSV 1e-5f

typedef unsigned short u16;
typedef __attribute__((ext_vector_type(4)))  float f32x4;
typedef __attribute__((ext_vector_type(16))) float f32x16;
typedef __attribute__((ext_vector_type(4)))  unsigned short u16x4;
typedef __attribute__((ext_vector_type(8)))  unsigned short u16x8;
typedef __attribute__((ext_vector_type(8)))  short s16x8;

// ---------- bf16 split helpers ----------
static __device__ __forceinline__ u16 bf16rne(float x){
  unsigned u = __float_as_uint(x);
  return (u16)((u + 0x7FFFu + ((u>>16)&1u)) >> 16);
}
static __device__ __forceinline__ void split2(float x, u16& h, u16& l){
  unsigned u = __float_as_uint(x);
  unsigned rh = (u + 0x7FFFu + ((u>>16)&1u)) & 0xFFFF0000u;
  h = (u16)(rh >> 16);
  float lf = x - __uint_as_float(rh);
  l = bf16rne(lf);
}

// ---------- degree / CSR build ----------
__global__ void k_init_deg(float* __restrict__ deg){
  int i = blockIdx.x*256 + threadIdx.x;
  if (i < NN) deg[i] = 1.0f;
}

__global__ void k_build(const int* __restrict__ ei, const float* __restrict__ ea,
                        int* __restrict__ cnt, float* __restrict__ deg){
  int e = blockIdx.x*256 + threadIdx.x;
  if (e < NE){
    int d = ei[NE + e];
    atomicAdd(&cnt[d], 1);
    atomicAdd(&deg[d], ea[3*e+2]);
  }
}

__global__ void k_fin_deg(const float* __restrict__ deg, float* __restrict__ dinv,
                          float* __restrict__ dinv2){
  int i = blockIdx.x*256 + threadIdx.x;
  if (i < NN){ float r = rsqrtf(deg[i]); dinv[i] = r; dinv2[i] = r*r; }
}

__global__ __launch_bounds__(1024) void k_scan(const int* __restrict__ cnt,
                                               int* __restrict__ rowptr,
                                               int* __restrict__ cursor){
  __shared__ int sums[1024];
  int t = threadIdx.x;
  int b0 = t*49, b1 = b0+49; if (b0 > NN) b0 = NN; if (b1 > NN) b1 = NN;
  int s = 0;
  for (int i = b0; i < b1; ++i) s += cnt[i];
  sums[t] = s; __syncthreads();
  for (int o = 1; o < 1024; o <<= 1){
    int v = (t >= o) ? sums[t-o] : 0;
    __syncthreads();
    sums[t] += v;
    __syncthreads();
  }
  int p = sums[t] - s;   // exclusive prefix
  for (int i = b0; i < b1; ++i){ rowptr[i] = p; cursor[i] = p; p += cnt[i]; }
  if (t == 1023) rowptr[NN] = sums[1023];
}

__global__ void k_fill(const int* __restrict__ ei, const float* __restrict__ ea,
                       const float* __restrict__ dinv, int* __restrict__ cursor,
                       int* __restrict__ csrc, float* __restrict__ ccf){
  int e = blockIdx.x*256 + threadIdx.x;
  if (e < NE){
    int s = ei[e], d = ei[NE+e];
    float w = ea[3*e+2];
    int p = atomicAdd(&cursor[d], 1);
    csrc[p] = s;
    ccf[p] = dinv[s]*w*dinv[d];
  }
}

// ---------- aggregation (CSR gather, fused seed): agg[i] = dinv2[i]*H[i] + sum coef*H[src] ----------
__global__ __launch_bounds__(256) void k_agg(
    const float* __restrict__ H, const int* __restrict__ rp,
    const int* __restrict__ cs, const float* __restrict__ cf,
    const float* __restrict__ dinv2, float* __restrict__ outp, int K)
{
  int node = blockIdx.x*4 + (threadIdx.x>>6);
  int lane = threadIdx.x & 63;
  if (node >= NN) return;
  int c = (blockIdx.y<<8) + lane*4;
  f32x4 acc = dinv2[node] * (*(const f32x4*)(H + (size_t)node*K + c));
  int e0 = rp[node], e1 = rp[node+1];
  for (int e = e0; e < e1; ++e){
    int s = cs[e]; float w = cf[e];
    f32x4 v = *(const f32x4*)(H + (size_t)s*K + c);
    acc += w * v;
  }
  *(f32x4*)(outp + (size_t)node*K + c) = acc;
}

// ---------- W transpose + split + pad: Wt[n][k] for n<Mpad (0 beyond M) ----------
__global__ void k_wsplit(const float* __restrict__ W, u16* __restrict__ th,
                         u16* __restrict__ tl, int K, int M, int Mpad){
  int idx = blockIdx.x*256 + threadIdx.x;
  if (idx >= K*Mpad) return;
  int k = idx / Mpad, n = idx % Mpad;
  float x = (n < M) ? W[(size_t)k*M + n] : 0.f;
  u16 h, l; split2(x, h, l);
  th[(size_t)n*K + k] = h;
  tl[(size_t)n*K + k] = l;
}

// ---------- split-bf16 MFMA GEMM: C[NN][M] = A[NN][K] @ Wt^T + bias ----------
#define SWZ(r) (((r)>>1)&3)
static __device__ __forceinline__ int offq(int r, int q){
  return r*32 + ((((q>>1) ^ SWZ(r)) & 3)<<3) + ((q&1)<<2);  // ushort units
}
static __device__ __forceinline__ s16x8 mk8(const u16* p0, const u16* p1){
  u16x4 a = *(const u16x4*)p0;
  u16x4 b = *(const u16x4*)p1;
  return __builtin_bit_cast(s16x8, __builtin_shufflevector(a, b, 0,1,2,3,4,5,6,7));
}

__global__ __launch_bounds__(256) void k_gemm(
    const float* __restrict__ A, const u16* __restrict__ Bh_g,
    const u16* __restrict__ Bl_g, const float* __restrict__ bias,
    float* __restrict__ C, int K, int M)
{
  __shared__ u16 Ah[4096], Al[4096], Bh[4096], Bl[4096];
  const int tid = threadIdx.x;
  const int row0 = blockIdx.y*128, col0 = blockIdx.x*128;
  const int lane = tid & 63;
  const int wave = tid >> 6;
  const int wr = wave >> 1, wc = wave & 1;

  f32x16 acc[2][2];
  #pragma unroll
  for (int m=0;m<2;++m)
    #pragma unroll
    for (int n=0;n<2;++n)
      #pragma unroll
      for (int t=0;t<16;++t) acc[m][n][t] = 0.f;

  f32x4 aR[4];
  u16x8 bRh[2], bRl[2];

  // preload tile 0
  #pragma unroll
  for (int i=0;i<4;++i){
    int ch = tid + i*256, r = ch>>3, kq = ch&7;
    int rg = row0 + r;
    if (rg < NN) aR[i] = *(const f32x4*)(A + (size_t)rg*K + kq*4);
    else { aR[i][0]=0.f; aR[i][1]=0.f; aR[i][2]=0.f; aR[i][3]=0.f; }
  }
  #pragma unroll
  for (int i=0;i<2;++i){
    int ch = tid + i*256, r = ch>>2, j = ch&3;
    size_t bo = (size_t)(col0 + r)*K + j*8;
    bRh[i] = *(const u16x8*)(Bh_g + bo);
    bRl[i] = *(const u16x8*)(Bl_g + bo);
  }

  for (int k0 = 0; k0 < K; k0 += 32){
    __syncthreads();
    // regs -> LDS (with bf16 split for A)
    #pragma unroll
    for (int i=0;i<4;++i){
      int ch = tid + i*256, r = ch>>3, kq = ch&7;
      u16x4 h4, l4;
      #pragma unroll
      for (int j=0;j<4;++j){ u16 hh, ll; split2(aR[i][j], hh, ll); h4[j]=hh; l4[j]=ll; }
      int o = offq(r, kq);
      *(u16x4*)&Ah[o] = h4;
      *(u16x4*)&Al[o] = l4;
    }
    #pragma unroll
    for (int i=0;i<2;++i){
      int ch = tid + i*256, r = ch>>2, j = ch&3;
      int o = r*32 + (((j ^ SWZ(r)) & 3)<<3);
      *(u16x8*)&Bh[o] = bRh[i];
      *(u16x8*)&Bl[o] = bRl[i];
    }
    __syncthreads();
    // prefetch next tile into regs (global latency hides under MFMA)
    if (k0 + 32 < K){
      #pragma unroll
      for (int i=0;i<4;++i){
        int ch = tid + i*256, r = ch>>3, kq = ch&7;
        int rg = row0 + r;
        if (rg < NN) aR[i] = *(const f32x4*)(A + (size_t)rg*K + (k0+32) + kq*4);
        else { aR[i][0]=0.f; aR[i][1]=0.f; aR[i][2]=0.f; aR[i][3]=0.f; }
      }
      #pragma unroll
      for (int i=0;i<2;++i){
        int ch = tid + i*256, r = ch>>2, j = ch&3;
        size_t bo = (size_t)(col0 + r)*K + (k0+32) + j*8;
        bRh[i] = *(const u16x8*)(Bh_g + bo);
        bRl[i] = *(const u16x8*)(Bl_g + bo);
      }
    }
    // compute: 2 k-halves x (2x2 frags) x 3 split-MFMAs
    #pragma unroll
    for (int c=0;c<2;++c){
      const int hg = lane>>5;
      const int q0 = c*4 + hg, q1 = q0 + 2;
      s16x8 fah[2], fal[2], fbh[2], fbl[2];
      #pragma unroll
      for (int m=0;m<2;++m){
        int r = wr*64 + m*32 + (lane&31);
        int o0 = offq(r,q0), o1 = offq(r,q1);
        fah[m] = mk8(&Ah[o0], &Ah[o1]);
        fal[m] = mk8(&Al[o0], &Al[o1]);
      }
      #pragma unroll
      for (int n=0;n<2;++n){
        int r = wc*64 + n*32 + (lane&31);
        int o0 = offq(r,q0), o1 = offq(r,q1);
        fbh[n] = mk8(&Bh[o0], &Bh[o1]);
        fbl[n] = mk8(&Bl[o0], &Bl[o1]);
      }
      #pragma unroll
      for (int m=0;m<2;++m)
        #pragma unroll
        for (int n=0;n<2;++n){
          acc[m][n] = __builtin_amdgcn_mfma_f32_32x32x16_bf16(fah[m], fbh[n], acc[m][n], 0,0,0);
          acc[m][n] = __builtin_amdgcn_mfma_f32_32x32x16_bf16(fah[m], fbl[n], acc[m][n], 0,0,0);
          acc[m][n] = __builtin_amdgcn_mfma_f32_32x32x16_bf16(fal[m], fbh[n], acc[m][n], 0,0,0);
        }
    }
  }

  // epilogue: C/D layout col=lane&31, row=(reg&3)+8*(reg>>2)+4*(lane>>5)
  #pragma unroll
  for (int n=0;n<2;++n){
    int cg = col0 + wc*64 + n*32 + (lane&31);
    float bv = (cg < M) ? bias[cg] : 0.f;
    #pragma unroll
    for (int m=0;m<2;++m){
      #pragma unroll
      for (int t=0;t<16;++t){
        int rg = row0 + wr*64 + m*32 + (t&3) + ((t>>2)&3)*8 + ((lane>>5)<<2);
        if (rg < NN && cg < M)
          C[(size_t)rg*M + cg] = acc[m][n][t] + bv;
      }
    }
  }
}

// ---------- batchnorm ----------
__global__ void k_bn_stats(const float* __restrict__ h, float* __restrict__ s1,
                           float* __restrict__ s2, int H){
  int c = blockIdx.x*blockDim.x + threadIdx.x;
  if (c >= H) return;
  int nch = gridDim.y;
  int rows_per = (NN + nch - 1)/nch;
  int r0 = blockIdx.y*rows_per;
  int r1 = r0 + rows_per; if (r1 > NN) r1 = NN;
  float a = 0.f, b = 0.f;
  for (int r = r0; r < r1; ++r){
    float v = h[(size_t)r*H + c];
    a += v; b += v*v;
  }
  atomicAdd(&s1[c], a);
  atomicAdd(&s2[c], b);
}

__global__ void k_bn_apply(float* __restrict__ h, const float* __restrict__ s1,
                           const float* __restrict__ s2, const float* __restrict__ g,
                           const float* __restrict__ be, int H){
  int i4 = blockIdx.x*256 + threadIdx.x;
  if (i4 >= NN*H/4) return;
  int c0 = (i4*4) % H;
  f32x4 v = *(f32x4*)(h + (size_t)i4*4);
  #pragma unroll
  for (int j=0;j<4;++j){
    int c = c0 + j;
    float m = s1[c]*(1.f/NN);
    float var = s2[c]*(1.f/NN) - m*m;
    float x = (v[j]-m)*rsqrtf(var+EPSV)*g[c] + be[c];
    v[j] = x > 0.f ? x : 0.f;
  }
  *(f32x4*)(h + (size_t)i4*4) = v;
}

extern "C" void kernel_launch(void* const* d_in, const int* in_sizes, int n_in,
                              void* d_out, int out_size, void* d_ws, size_t ws_size,
                              hipStream_t stream){
  const float* x   = (const float*)d_in[0];
  const int*   ei  = (const int*)d_in[1];
  const float* ea  = (const float*)d_in[2];
  const float* W1  = (const float*)d_in[4];
  const float* b1  = (const float*)d_in[5];
  const float* g1  = (const float*)d_in[6];
  const float* be1 = (const float*)d_in[7];
  const float* W2  = (const float*)d_in[8];
  const float* b2  = (const float*)d_in[9];
  const float* g2  = (const float*)d_in[10];
  const float* be2 = (const float*)d_in[11];
  const float* W3  = (const float*)d_in[12];
  const float* b3  = (const float*)d_in[13];
  float* out = (float*)d_out;

  // workspace layout (16B-aligned sections)
  char* p = (char*)d_ws;
  int*   cnt    = (int*)p;   p += (size_t)NN*4;
  int*   cursor = (int*)p;   p += (size_t)NN*4;
  int*   rowptr = (int*)p;   p += (size_t)(NN+4)*4;
  float* deg    = (float*)p; p += (size_t)NN*4;
  float* dinv   = (float*)p; p += (size_t)NN*4;
  float* dinv2  = (float*)p; p += (size_t)NN*4;
  int*   csrc   = (int*)p;   p += (size_t)NE*4;
  float* ccf    = (float*)p; p += (size_t)NE*4;
  u16*   Wth    = (u16*)p;   p += (size_t)3072*1024*2;
  u16*   Wtl    = (u16*)p;   p += (size_t)3072*1024*2;
  float* s1     = (float*)p; p += 1024*4;
  float* s2     = (float*)p; p += 1024*4;
  float* agg    = (float*)p;                        // NN*1024 f32 = 204.8 MB

  // stage intermediates inside d_out (dead before final GEMM rewrites it)
  float* h1 = out;                       // NN*512
  float* h2 = out + (size_t)NN*512;      // NN*1024

  const int T = 256;
  const int gN = (NN+T-1)/T, gE = NE/T;

  // graph prep
  hipMemsetAsync(cnt, 0, (size_t)NN*4, stream);
  k_init_deg<<<gN,T,0,stream>>>(deg);
  k_build<<<gE,T,0,stream>>>(ei, ea, cnt, deg);
  k_fin_deg<<<gN,T,0,stream>>>(deg, dinv, dinv2);
  k_scan<<<1,1024,0,stream>>>(cnt, rowptr, cursor);
  k_fill<<<gE,T,0,stream>>>(ei, ea, dinv, cursor, csrc, ccf);

  // ----- layer 1: K=256 -> M=512 -----
  k_agg<<<dim3(NN/4,1),T,0,stream>>>(x, rowptr, csrc, ccf, dinv2, agg, 256);
  k_wsplit<<<(256*512)/T,T,0,stream>>>(W1, Wth, Wtl, 256, 512, 512);
  k_gemm<<<dim3(4,(NN+127)/128),T,0,stream>>>(agg, Wth, Wtl, b1, h1, 256, 512);
  hipMemsetAsync(s1, 0, 2*1024*4, stream);
  k_bn_stats<<<dim3(2,128),T,0,stream>>>(h1, s1, s2, 512);
  k_bn_apply<<<(NN*512/4)/T,T,0,stream>>>(h1, s1, s2, g1, be1, 512);

  // ----- layer 2: K=512 -> M=1024 -----
  k_agg<<<dim3(NN/4,2),T,0,stream>>>(h1, rowptr, csrc, ccf, dinv2, agg, 512);
  k_wsplit<<<(512*1024)/T,T,0,stream>>>(W2, Wth, Wtl, 512, 1024, 1024);
  k_gemm<<<dim3(8,(NN+127)/128),T,0,stream>>>(agg, Wth, Wtl, b2, h2, 512, 1024);
  hipMemsetAsync(s1, 0, 2*1024*4, stream);
  k_bn_stats<<<dim3(4,128),T,0,stream>>>(h2, s1, s2, 1024);
  k_bn_apply<<<(NN*1024/4)/T,T,0,stream>>>(h2, s1, s2, g2, be2, 1024);

  // ----- layer 3: K=1024 -> M=3000 (pad 3072) -----
  k_agg<<<dim3(NN/4,4),T,0,stream>>>(h2, rowptr, csrc, ccf, dinv2, agg, 1024);
  k_wsplit<<<(1024*3072)/T,T,0,stream>>>(W3, Wth, Wtl, 1024, 3000, 3072);
  k_gemm<<<dim3(24,(NN+127)/128),T,0,stream>>>(agg, Wth, Wtl, b3, out, 1024, 3000);
}

// Round 3
// 2181.647 us; speedup vs baseline: 5.7558x; 1.5917x over previous
//
#include <hip/hip_runtime.h>

#define NN 50000
#define NE 800000
#define EPSV 1e-5f

typedef _Float16 f16;
typedef __attribute__((ext_vector_type(4)))  float f32x4;
typedef __attribute__((ext_vector_type(16))) float f32x16;
typedef __attribute__((ext_vector_type(8)))  f16 f16x8;
typedef __attribute__((ext_vector_type(4)))  f16 f16x4;

// permuted k order within each 16-group: quads [0,2,1,3] so each MFMA fragment
// (lane-lo: {0-3,8-11}, lane-hi: {4-7,12-15}) is one contiguous 16B chunk.
static __device__ __forceinline__ int kperm(int k){
  int q = (k>>2)&3;
  int p = ((q&1)<<1) | (q>>1);
  return (k & ~15) + (p<<2) + (k&3);
}

// ---------- degree / CSR build ----------
__global__ void k_init_deg(float* __restrict__ deg){
  int i = blockIdx.x*256 + threadIdx.x;
  if (i < NN) deg[i] = 1.0f;
}

__global__ void k_build(const int* __restrict__ ei, const float* __restrict__ ea,
                        int* __restrict__ cnt, float* __restrict__ deg){
  int e = blockIdx.x*256 + threadIdx.x;
  if (e < NE){
    int d = ei[NE + e];
    atomicAdd(&cnt[d], 1);
    atomicAdd(&deg[d], ea[3*e+2]);
  }
}

__global__ void k_fin_deg(const float* __restrict__ deg, float* __restrict__ dinv,
                          float* __restrict__ dinv2){
  int i = blockIdx.x*256 + threadIdx.x;
  if (i < NN){ float r = rsqrtf(deg[i]); dinv[i] = r; dinv2[i] = r*r; }
}

__global__ __launch_bounds__(1024) void k_scan(const int* __restrict__ cnt,
                                               int* __restrict__ rowptr,
                                               int* __restrict__ cursor){
  __shared__ int sums[1024];
  int t = threadIdx.x;
  int b0 = t*49, b1 = b0+49; if (b0 > NN) b0 = NN; if (b1 > NN) b1 = NN;
  int s = 0;
  for (int i = b0; i < b1; ++i) s += cnt[i];
  sums[t] = s; __syncthreads();
  for (int o = 1; o < 1024; o <<= 1){
    int v = (t >= o) ? sums[t-o] : 0;
    __syncthreads();
    sums[t] += v;
    __syncthreads();
  }
  int p = sums[t] - s;
  for (int i = b0; i < b1; ++i){ rowptr[i] = p; cursor[i] = p; p += cnt[i]; }
  if (t == 1023) rowptr[NN] = sums[1023];
}

__global__ void k_fill(const int* __restrict__ ei, const float* __restrict__ ea,
                       const float* __restrict__ dinv, int* __restrict__ cursor,
                       int* __restrict__ csrc, float* __restrict__ ccf){
  int e = blockIdx.x*256 + threadIdx.x;
  if (e < NE){
    int s = ei[e], d = ei[NE+e];
    float w = ea[3*e+2];
    int p = atomicAdd(&cursor[d], 1);
    csrc[p] = s;
    ccf[p] = dinv[s]*w*dinv[d];
  }
}

// ---------- x f32 -> fp16 (k-permuted) ----------
__global__ void k_xconv(const float* __restrict__ x, f16* __restrict__ xh){
  int idx = blockIdx.x*256 + threadIdx.x;      // quad index
  if (idx >= NN*64) return;                     // 256/4 quads per row
  int node = idx >> 6, k = (idx & 63)*4;
  f32x4 v = *(const f32x4*)(x + (size_t)node*256 + k);
  f16x4 h;
  #pragma unroll
  for (int j=0;j<4;++j) h[j] = (f16)v[j];
  *(f16x4*)(xh + (size_t)node*256 + kperm(k)) = h;
}

// ---------- W transpose -> fp16 [n][k] (k-permuted, n zero-padded) ----------
__global__ void k_w16(const float* __restrict__ W, f16* __restrict__ Wt,
                      int K, int M, int Mpad){
  int idx = blockIdx.x*256 + threadIdx.x;
  if (idx >= K*Mpad) return;
  int k = idx / Mpad, n = idx % Mpad;
  float v = (n < M) ? W[(size_t)k*M + n] : 0.f;
  Wt[(size_t)n*K + kperm(k)] = (f16)v;
}

// ---------- aggregation (CSR gather, fp16 in/out, f32 accum) ----------
__global__ __launch_bounds__(256) void k_agg16(
    const f16* __restrict__ H, const int* __restrict__ rp,
    const int* __restrict__ cs, const float* __restrict__ cf,
    const float* __restrict__ dinv2, f16* __restrict__ outp, int K)
{
  int node = blockIdx.x*4 + (threadIdx.x>>6);
  int lane = threadIdx.x & 63;
  if (node >= NN) return;
  int c = (blockIdx.y<<8) + lane*4;
  f16x4 hv = *(const f16x4*)(H + (size_t)node*K + c);
  float d2 = dinv2[node];
  f32x4 acc;
  #pragma unroll
  for (int j=0;j<4;++j) acc[j] = d2*(float)hv[j];
  int e0 = rp[node], e1 = rp[node+1];
  for (int e = e0; e < e1; ++e){
    int s = cs[e]; float w = cf[e];
    f16x4 v = *(const f16x4*)(H + (size_t)s*K + c);
    #pragma unroll
    for (int j=0;j<4;++j) acc[j] += w*(float)v[j];
  }
  f16x4 o;
  #pragma unroll
  for (int j=0;j<4;++j) o[j] = (f16)acc[j];
  *(f16x4*)(outp + (size_t)node*K + c) = o;
}

// ---------- fp16 MFMA GEMM (m97 structure): C[rows][M] = A @ Wt^T + bias ----------
// A: fp16 [rows(padded)][K] k-permuted; Wt: fp16 [Mpad][K] k-permuted.
// LDS linear via global_load_lds; chunk swizzle phi(r)=(r>>1)&3 pre-applied on
// per-lane global source and re-applied on ds_read (both-sides involution).
__global__ __launch_bounds__(256) void k_gemm16(
    const f16* __restrict__ A, const f16* __restrict__ B,
    const float* __restrict__ bias, float* __restrict__ C,
    int K, int M)
{
  __shared__ f16 Ah[128*32];
  __shared__ f16 Bh[128*32];
  const int tid  = threadIdx.x;
  const int lane = tid & 63;
  const int wave = tid >> 6;
  const int wr = wave >> 1, wc = wave & 1;

  // XCD-aware block swizzle (bijective only when nwg % 8 == 0)
  int nwg = gridDim.x*gridDim.y;
  int bid = blockIdx.y*gridDim.x + blockIdx.x;
  if ((nwg & 7) == 0){
    int cpx = nwg >> 3;
    bid = (bid & 7)*cpx + (bid >> 3);
  }
  const int bx = bid % gridDim.x, by = bid / gridDim.x;
  const int row0 = by*128, col0 = bx*128;

  f32x16 acc[2][2];
  #pragma unroll
  for (int m=0;m<2;++m)
    #pragma unroll
    for (int n=0;n<2;++n)
      #pragma unroll
      for (int t=0;t<16;++t) acc[m][n][t] = 0.f;

  for (int k0 = 0; k0 < K; k0 += 32){
    __syncthreads();   // protect LDS from readers of previous tile
    // stage A,B tiles: 2 issues each, 16B/lane, LDS linear
    #pragma unroll
    for (int i=0;i<2;++i){
      int phys = i*256 + tid;          // 16B chunk index in LDS
      int rp = phys >> 2, cp = phys & 3;
      int sc = cp ^ ((rp>>1)&3);       // inverse swizzle on global source
      const f16* srcA = A + (size_t)(row0+rp)*K + k0 + sc*8;
      const f16* srcB = B + (size_t)(col0+rp)*K + k0 + sc*8;
      f16* dstA = &Ah[(size_t)(i*256 + (wave<<6))*8];   // wave-uniform base
      f16* dstB = &Bh[(size_t)(i*256 + (wave<<6))*8];
      __builtin_amdgcn_global_load_lds((const unsigned int*)srcA, (unsigned int*)dstA, 16, 0, 0);
      __builtin_amdgcn_global_load_lds((const unsigned int*)srcB, (unsigned int*)dstB, 16, 0, 0);
    }
    __syncthreads();   // compiler drains vmcnt before barrier

    const int hg = lane >> 5;
    #pragma unroll
    for (int c=0;c<2;++c){
      f16x8 fa[2], fb[2];
      #pragma unroll
      for (int m=0;m<2;++m){
        int r = wr*64 + m*32 + (lane&31);
        int u = c*2 + hg;
        fa[m] = *(const f16x8*)&Ah[r*32 + ((u ^ ((r>>1)&3))<<3)];
      }
      #pragma unroll
      for (int n=0;n<2;++n){
        int r = wc*64 + n*32 + (lane&31);
        int u = c*2 + hg;
        fb[n] = *(const f16x8*)&Bh[r*32 + ((u ^ ((r>>1)&3))<<3)];
      }
      #pragma unroll
      for (int m=0;m<2;++m)
        #pragma unroll
        for (int n=0;n<2;++n)
          acc[m][n] = __builtin_amdgcn_mfma_f32_32x32x16_f16(fa[m], fb[n], acc[m][n], 0,0,0);
    }
  }

  // epilogue: C/D 32x32 layout col=lane&31, row=(t&3)+8*((t>>2)&3)+4*(lane>>5)
  #pragma unroll
  for (int n=0;n<2;++n){
    int cg = col0 + wc*64 + n*32 + (lane&31);
    float bv = (cg < M) ? bias[cg] : 0.f;
    #pragma unroll
    for (int m=0;m<2;++m){
      #pragma unroll
      for (int t=0;t<16;++t){
        int rg = row0 + wr*64 + m*32 + (t&3) + ((t>>2)&3)*8 + ((lane>>5)<<2);
        if (rg < NN && cg < M)
          C[(size_t)rg*M + cg] = acc[m][n][t] + bv;
      }
    }
  }
}

// ---------- batchnorm ----------
__global__ void k_bn_stats(const float* __restrict__ h, float* __restrict__ s1,
                           float* __restrict__ s2, int H){
  int c = blockIdx.x*blockDim.x + threadIdx.x;
  if (c >= H) return;
  int nch = gridDim.y;
  int rows_per = (NN + nch - 1)/nch;
  int r0 = blockIdx.y*rows_per;
  int r1 = r0 + rows_per; if (r1 > NN) r1 = NN;
  float a = 0.f, b = 0.f;
  for (int r = r0; r < r1; ++r){
    float v = h[(size_t)r*H + c];
    a += v; b += v*v;
  }
  atomicAdd(&s1[c], a);
  atomicAdd(&s2[c], b);
}

// BN+ReLU, f32 in -> fp16 out (k-permuted for next GEMM's A)
__global__ void k_bn_apply16(const float* __restrict__ hf, const float* __restrict__ s1,
                             const float* __restrict__ s2, const float* __restrict__ g,
                             const float* __restrict__ be, f16* __restrict__ hh, int H){
  int i4 = blockIdx.x*256 + threadIdx.x;
  if (i4 >= NN*H/4) return;
  int c0 = (i4*4) % H;
  int node = (i4*4) / H;
  f32x4 v = *(const f32x4*)(hf + (size_t)i4*4);
  f16x4 o;
  #pragma unroll
  for (int j=0;j<4;++j){
    int c = c0 + j;
    float m = s1[c]*(1.f/NN);
    float var = s2[c]*(1.f/NN) - m*m;
    float x = (v[j]-m)*rsqrtf(var+EPSV)*g[c] + be[c];
    o[j] = (f16)(x > 0.f ? x : 0.f);
  }
  *(f16x4*)(hh + (size_t)node*H + kperm(c0)) = o;
}

extern "C" void kernel_launch(void* const* d_in, const int* in_sizes, int n_in,
                              void* d_out, int out_size, void* d_ws, size_t ws_size,
                              hipStream_t stream){
  const float* x   = (const float*)d_in[0];
  const int*   ei  = (const int*)d_in[1];
  const float* ea  = (const float*)d_in[2];
  const float* W1  = (const float*)d_in[4];
  const float* b1  = (const float*)d_in[5];
  const float* g1  = (const float*)d_in[6];
  const float* be1 = (const float*)d_in[7];
  const float* W2  = (const float*)d_in[8];
  const float* b2  = (const float*)d_in[9];
  const float* g2  = (const float*)d_in[10];
  const float* be2 = (const float*)d_in[11];
  const float* W3  = (const float*)d_in[12];
  const float* b3  = (const float*)d_in[13];
  float* out = (float*)d_out;

  // ---- workspace ----
  char* p = (char*)d_ws;
  int*   cnt    = (int*)p;   p += (size_t)NN*4;
  int*   cursor = (int*)p;   p += (size_t)NN*4;
  int*   rowptr = (int*)p;   p += (size_t)(NN+4)*4;
  float* deg    = (float*)p; p += (size_t)NN*4;
  float* dinv   = (float*)p; p += (size_t)NN*4;
  float* dinv2  = (float*)p; p += (size_t)NN*4;
  int*   csrc   = (int*)p;   p += (size_t)NE*4;
  float* ccf    = (float*)p; p += (size_t)NE*4;
  f16*   Wt     = (f16*)p;   p += (size_t)3072*1024*2;
  float* s1     = (float*)p; p += 1024*4;
  float* s2     = (float*)p; p += 1024*4;
  f16*   aggh   = (f16*)p;   p += (size_t)50176*1024*2;  // padded rows

  // ---- stage in d_out (all dead before final GEMM rewrites d_out) ----
  float* h1f = out;                         // NN*512 f32
  float* h2f = out + (size_t)NN*512;        // NN*1024 f32
  f16*   xh  = (f16*)(out + (size_t)NN*1536);            // NN*256 f16
  f16*   h1h = xh  + (size_t)NN*256;                     // NN*512 f16
  f16*   h2h = h1h + (size_t)NN*512;                     // NN*1024 f16

  const int T = 256;
  const int gN = (NN+T-1)/T, gE = NE/T;
  const int GR = (NN+127)/128;  // 391 row-blocks

  // graph prep
  hipMemsetAsync(cnt, 0, (size_t)NN*4, stream);
  k_init_deg<<<gN,T,0,stream>>>(deg);
  k_build<<<gE,T,0,stream>>>(ei, ea, cnt, deg);
  k_fin_deg<<<gN,T,0,stream>>>(deg, dinv, dinv2);
  k_scan<<<1,1024,0,stream>>>(cnt, rowptr, cursor);
  k_fill<<<gE,T,0,stream>>>(ei, ea, dinv, cursor, csrc, ccf);
  k_xconv<<<(NN*64+T-1)/T,T,0,stream>>>(x, xh);

  // ----- layer 1: K=256 -> M=512 -----
  k_agg16<<<dim3(NN/4,1),T,0,stream>>>(xh, rowptr, csrc, ccf, dinv2, aggh, 256);
  k_w16<<<(256*512)/T,T,0,stream>>>(W1, Wt, 256, 512, 512);
  k_gemm16<<<dim3(4,GR),T,0,stream>>>(aggh, Wt, b1, h1f, 256, 512);
  hipMemsetAsync(s1, 0, 2*1024*4, stream);
  k_bn_stats<<<dim3(2,128),T,0,stream>>>(h1f, s1, s2, 512);
  k_bn_apply16<<<(NN*512/4)/T,T,0,stream>>>(h1f, s1, s2, g1, be1, h1h, 512);

  // ----- layer 2: K=512 -> M=1024 -----
  k_agg16<<<dim3(NN/4,2),T,0,stream>>>(h1h, rowptr, csrc, ccf, dinv2, aggh, 512);
  k_w16<<<(512*1024)/T,T,0,stream>>>(W2, Wt, 512, 1024, 1024);
  k_gemm16<<<dim3(8,GR),T,0,stream>>>(aggh, Wt, b2, h2f, 512, 1024);
  hipMemsetAsync(s1, 0, 2*1024*4, stream);
  k_bn_stats<<<dim3(4,128),T,0,stream>>>(h2f, s1, s2, 1024);
  k_bn_apply16<<<(NN*1024/4)/T,T,0,stream>>>(h2f, s1, s2, g2, be2, h2h, 1024);

  // ----- layer 3: K=1024 -> M=3000 (pad 3072) -----
  k_agg16<<<dim3(NN/4,4),T,0,stream>>>(h2h, rowptr, csrc, ccf, dinv2, aggh, 1024);
  k_w16<<<(1024*3072)/T,T,0,stream>>>(W3, Wt, 1024, 3000, 3072);
  k_gemm16<<<dim3(24,GR),T,0,stream>>>(aggh, Wt, b3, out, 1024, 3000);
}

// Round 5
// 1954.506 us; speedup vs baseline: 6.4248x; 1.1162x over previous
//
#include <hip/hip_runtime.h>

#define NN 50000
#define NE 800000
#define EPSV 1e-5f

typedef _Float16 f16;
typedef __attribute__((ext_vector_type(4)))  float f32x4;
typedef __attribute__((ext_vector_type(16))) float f32x16;
typedef __attribute__((ext_vector_type(8)))  f16 f16x8;
typedef __attribute__((ext_vector_type(4)))  f16 f16x4;

// permuted k order within each 16-group: quads [0,2,1,3] so each MFMA fragment
// (lane-lo: {0-3,8-11}, lane-hi: {4-7,12-15}) is one contiguous 16B chunk.
// involution: kperm(kperm(k)) == k; preserves offset within a quad.
static __device__ __forceinline__ int kperm(int k){
  int q = (k>>2)&3;
  int p = ((q&1)<<1) | (q>>1);
  return (k & ~15) + (p<<2) + (k&3);
}

// ---------- degree / CSR build ----------
__global__ void k_init_deg(float* __restrict__ deg){
  int i = blockIdx.x*256 + threadIdx.x;
  if (i < NN) deg[i] = 1.0f;
}

__global__ void k_build(const int* __restrict__ ei, const float* __restrict__ ea,
                        int* __restrict__ cnt, float* __restrict__ deg){
  int e = blockIdx.x*256 + threadIdx.x;
  if (e < NE){
    int d = ei[NE + e];
    atomicAdd(&cnt[d], 1);
    atomicAdd(&deg[d], ea[3*e+2]);
  }
}

__global__ void k_fin_deg(const float* __restrict__ deg, float* __restrict__ dinv,
                          float* __restrict__ dinv2){
  int i = blockIdx.x*256 + threadIdx.x;
  if (i < NN){ float r = rsqrtf(deg[i]); dinv[i] = r; dinv2[i] = r*r; }
}

__global__ __launch_bounds__(1024) void k_scan(const int* __restrict__ cnt,
                                               int* __restrict__ rowptr,
                                               int* __restrict__ cursor){
  __shared__ int sums[1024];
  int t = threadIdx.x;
  int b0 = t*49, b1 = b0+49; if (b0 > NN) b0 = NN; if (b1 > NN) b1 = NN;
  int s = 0;
  for (int i = b0; i < b1; ++i) s += cnt[i];
  sums[t] = s; __syncthreads();
  for (int o = 1; o < 1024; o <<= 1){
    int v = (t >= o) ? sums[t-o] : 0;
    __syncthreads();
    sums[t] += v;
    __syncthreads();
  }
  int p = sums[t] - s;
  for (int i = b0; i < b1; ++i){ rowptr[i] = p; cursor[i] = p; p += cnt[i]; }
  if (t == 1023) rowptr[NN] = sums[1023];
}

__global__ void k_fill(const int* __restrict__ ei, const float* __restrict__ ea,
                       const float* __restrict__ dinv, int* __restrict__ cursor,
                       int* __restrict__ csrc, float* __restrict__ ccf){
  int e = blockIdx.x*256 + threadIdx.x;
  if (e < NE){
    int s = ei[e], d = ei[NE+e];
    float w = ea[3*e+2];
    int p = atomicAdd(&cursor[d], 1);
    csrc[p] = s;
    ccf[p] = dinv[s]*w*dinv[d];
  }
}

// ---------- x f32 -> fp16 (k-permuted) ----------
__global__ void k_xconv(const float* __restrict__ x, f16* __restrict__ xh){
  int idx = blockIdx.x*256 + threadIdx.x;      // quad index
  if (idx >= NN*64) return;
  int node = idx >> 6, k = (idx & 63)*4;
  f32x4 v = *(const f32x4*)(x + (size_t)node*256 + k);
  f16x4 h;
  #pragma unroll
  for (int j=0;j<4;++j) h[j] = (f16)v[j];
  *(f16x4*)(xh + (size_t)node*256 + kperm(k)) = h;
}

// ---------- W transpose -> fp16 [n][k] (k-permuted, n zero-padded) ----------
__global__ void k_w16(const float* __restrict__ W, f16* __restrict__ Wt,
                      int K, int M, int Mpad){
  int idx = blockIdx.x*256 + threadIdx.x;
  if (idx >= K*Mpad) return;
  int k = idx / Mpad, n = idx % Mpad;
  float v = (n < M) ? W[(size_t)k*M + n] : 0.f;
  Wt[(size_t)n*K + kperm(k)] = (f16)v;
}

// ---------- aggregation (CSR gather), optional fused BN+ReLU on the INPUT ----------
// All f16 activations are stored k-permuted. s1/s2 are indexed by STORED col
// (the GEMM epilogue deposits them there); g/be are indexed by ACTUAL col.
template<bool BN>
__global__ __launch_bounds__(256) void k_agg16(
    const f16* __restrict__ H, const int* __restrict__ rp,
    const int* __restrict__ cs, const float* __restrict__ cf,
    const float* __restrict__ dinv2,
    const float* __restrict__ s1, const float* __restrict__ s2,
    const float* __restrict__ g, const float* __restrict__ be,
    f16* __restrict__ outp, int K)
{
  int node = blockIdx.x*4 + (threadIdx.x>>6);
  int lane = threadIdx.x & 63;
  if (node >= NN) return;
  int c = (blockIdx.y<<8) + lane*4;      // stored (permuted) col, quad-aligned
  float av[4], bv[4];
  if (BN){
    int qa = kperm(c);                   // actual col of quad base
    #pragma unroll
    for (int j=0;j<4;++j){
      float mm = s1[c+j]*(1.f/NN);
      float var = s2[c+j]*(1.f/NN) - mm*mm;
      float sc = rsqrtf(var+EPSV)*g[qa+j];
      av[j] = sc;
      bv[j] = be[qa+j] - mm*sc;
    }
  }
  f16x4 hv = *(const f16x4*)(H + (size_t)node*K + c);
  float d2 = dinv2[node];
  f32x4 acc;
  #pragma unroll
  for (int j=0;j<4;++j){
    float v = (float)hv[j];
    if (BN){ v = fmaf(v, av[j], bv[j]); v = v > 0.f ? v : 0.f; }
    acc[j] = d2*v;
  }
  int e0 = rp[node], e1 = rp[node+1];
  for (int e = e0; e < e1; ++e){
    int s = cs[e]; float w = cf[e];
    f16x4 v4 = *(const f16x4*)(H + (size_t)s*K + c);
    #pragma unroll
    for (int j=0;j<4;++j){
      float v = (float)v4[j];
      if (BN){ v = fmaf(v, av[j], bv[j]); v = v > 0.f ? v : 0.f; }
      acc[j] += w*v;
    }
  }
  f16x4 o;
  #pragma unroll
  for (int j=0;j<4;++j) o[j] = (f16)acc[j];
  *(f16x4*)(outp + (size_t)node*K + c) = o;
}

// ---------- fp16 MFMA GEMM (m97 structure) ----------
// STATS=true: write f16 at k-PERMUTED column position (next GEMM's A layout),
//             accumulate per-stored-column sum/sumsq into s1/s2. No bias (BN
//             mean-subtraction cancels it).
// STATS=false: write f32 + bias at actual column position (final output).
template<bool STATS>
__global__ __launch_bounds__(256) void k_gemm16(
    const f16* __restrict__ A, const f16* __restrict__ B,
    const float* __restrict__ bias, float* __restrict__ Cf,
    f16* __restrict__ Ch, float* __restrict__ s1, float* __restrict__ s2,
    int K, int M)
{
  __shared__ f16 Ah[128*32];
  __shared__ f16 Bh[128*32];
  const int tid  = threadIdx.x;
  const int lane = tid & 63;
  const int wave = tid >> 6;
  const int wr = wave >> 1, wc = wave & 1;

  int nwg = gridDim.x*gridDim.y;
  int bid = blockIdx.y*gridDim.x + blockIdx.x;
  if ((nwg & 7) == 0){
    int cpx = nwg >> 3;
    bid = (bid & 7)*cpx + (bid >> 3);
  }
  const int bx = bid % gridDim.x, by = bid / gridDim.x;
  const int row0 = by*128, col0 = bx*128;

  f32x16 acc[2][2];
  #pragma unroll
  for (int m=0;m<2;++m)
    #pragma unroll
    for (int n=0;n<2;++n)
      #pragma unroll
      for (int t=0;t<16;++t) acc[m][n][t] = 0.f;

  for (int k0 = 0; k0 < K; k0 += 32){
    __syncthreads();
    #pragma unroll
    for (int i=0;i<2;++i){
      int phys = i*256 + tid;
      int rp = phys >> 2, cp = phys & 3;
      int sc = cp ^ ((rp>>1)&3);
      const f16* srcA = A + (size_t)(row0+rp)*K + k0 + sc*8;
      const f16* srcB = B + (size_t)(col0+rp)*K + k0 + sc*8;
      f16* dstA = &Ah[(size_t)(i*256 + (wave<<6))*8];
      f16* dstB = &Bh[(size_t)(i*256 + (wave<<6))*8];
      __builtin_amdgcn_global_load_lds((const unsigned int*)srcA, (unsigned int*)dstA, 16, 0, 0);
      __builtin_amdgcn_global_load_lds((const unsigned int*)srcB, (unsigned int*)dstB, 16, 0, 0);
    }
    __syncthreads();

    const int hg = lane >> 5;
    #pragma unroll
    for (int c=0;c<2;++c){
      f16x8 fa[2], fb[2];
      #pragma unroll
      for (int m=0;m<2;++m){
        int r = wr*64 + m*32 + (lane&31);
        int u = c*2 + hg;
        fa[m] = *(const f16x8*)&Ah[r*32 + ((u ^ ((r>>1)&3))<<3)];
      }
      #pragma unroll
      for (int n=0;n<2;++n){
        int r = wc*64 + n*32 + (lane&31);
        int u = c*2 + hg;
        fb[n] = *(const f16x8*)&Bh[r*32 + ((u ^ ((r>>1)&3))<<3)];
      }
      #pragma unroll
      for (int m=0;m<2;++m)
        #pragma unroll
        for (int n=0;n<2;++n)
          acc[m][n] = __builtin_amdgcn_mfma_f32_32x32x16_f16(fa[m], fb[n], acc[m][n], 0,0,0);
    }
  }

  // epilogue: C/D 32x32 layout col=lane&31, row=(t&3)+8*((t>>2)&3)+4*(lane>>5)
  #pragma unroll
  for (int n=0;n<2;++n){
    int cg = col0 + wc*64 + n*32 + (lane&31);   // ACTUAL output column
    if (STATS){
      int cp = kperm(cg);                       // STORED (permuted) position
      float sum = 0.f, sq = 0.f;
      #pragma unroll
      for (int m=0;m<2;++m){
        #pragma unroll
        for (int t=0;t<16;++t){
          int rg = row0 + wr*64 + m*32 + (t&3) + ((t>>2)&3)*8 + ((lane>>5)<<2);
          if (rg < NN){
            float v = acc[m][n][t];
            sum += v; sq += v*v;
            Ch[(size_t)rg*M + cp] = (f16)v;
          }
        }
      }
      atomicAdd(&s1[cp], sum);
      atomicAdd(&s2[cp], sq);
    } else {
      float bv = (cg < M) ? bias[cg] : 0.f;
      #pragma unroll
      for (int m=0;m<2;++m){
        #pragma unroll
        for (int t=0;t<16;++t){
          int rg = row0 + wr*64 + m*32 + (t&3) + ((t>>2)&3)*8 + ((lane>>5)<<2);
          if (rg < NN && cg < M)
            Cf[(size_t)rg*M + cg] = acc[m][n][t] + bv;
        }
      }
    }
  }
}

extern "C" void kernel_launch(void* const* d_in, const int* in_sizes, int n_in,
                              void* d_out, int out_size, void* d_ws, size_t ws_size,
                              hipStream_t stream){
  const float* x   = (const float*)d_in[0];
  const int*   ei  = (const int*)d_in[1];
  const float* ea  = (const float*)d_in[2];
  const float* W1  = (const float*)d_in[4];
  const float* g1  = (const float*)d_in[6];
  const float* be1 = (const float*)d_in[7];
  const float* W2  = (const float*)d_in[8];
  const float* g2  = (const float*)d_in[10];
  const float* be2 = (const float*)d_in[11];
  const float* W3  = (const float*)d_in[12];
  const float* b3  = (const float*)d_in[13];
  float* out = (float*)d_out;

  // ---- workspace ----
  char* p = (char*)d_ws;
  int*   cnt    = (int*)p;   p += (size_t)NN*4;
  int*   cursor = (int*)p;   p += (size_t)NN*4;
  int*   rowptr = (int*)p;   p += (size_t)(NN+4)*4;
  float* deg    = (float*)p; p += (size_t)NN*4;
  float* dinv   = (float*)p; p += (size_t)NN*4;
  float* dinv2  = (float*)p; p += (size_t)NN*4;
  int*   csrc   = (int*)p;   p += (size_t)NE*4;
  float* ccf    = (float*)p; p += (size_t)NE*4;
  f16*   Wt     = (f16*)p;   p += (size_t)3072*1024*2;
  float* s1a    = (float*)p; p += 1024*4;   // layer-1 stats (512 used)
  float* s2a    = (float*)p; p += 1024*4;
  float* s1b    = (float*)p; p += 1024*4;   // layer-2 stats
  float* s2b    = (float*)p; p += 1024*4;
  f16*   aggh   = (f16*)p;   p += (size_t)50176*1024*2;  // padded rows

  // ---- stage in d_out (dead before final GEMM rewrites d_out) ----
  f16* xh  = (f16*)out;                    // NN*256 f16
  f16* h1h = xh  + (size_t)NN*256;         // NN*512 f16  (raw GEMM1 out, permuted)
  f16* h2h = h1h + (size_t)NN*512;         // NN*1024 f16 (raw GEMM2 out, permuted)

  const int T = 256;
  const int gN = (NN+T-1)/T, gE = NE/T;
  const int GR = (NN+127)/128;  // 391 row-blocks

  // graph prep
  hipMemsetAsync(cnt, 0, (size_t)NN*4, stream);
  hipMemsetAsync(s1a, 0, 4*1024*4, stream);   // zero all four stat buffers
  k_init_deg<<<gN,T,0,stream>>>(deg);
  k_build<<<gE,T,0,stream>>>(ei, ea, cnt, deg);
  k_fin_deg<<<gN,T,0,stream>>>(deg, dinv, dinv2);
  k_scan<<<1,1024,0,stream>>>(cnt, rowptr, cursor);
  k_fill<<<gE,T,0,stream>>>(ei, ea, dinv, cursor, csrc, ccf);
  k_xconv<<<(NN*64+T-1)/T,T,0,stream>>>(x, xh);

  // ----- layer 1: agg(x) -> GEMM1 (f16 permuted out + stats) -----
  k_agg16<false><<<dim3(NN/4,1),T,0,stream>>>(xh, rowptr, csrc, ccf, dinv2,
                                              nullptr,nullptr,nullptr,nullptr, aggh, 256);
  k_w16<<<(256*512)/T,T,0,stream>>>(W1, Wt, 256, 512, 512);
  k_gemm16<true><<<dim3(4,GR),T,0,stream>>>(aggh, Wt, nullptr, nullptr, h1h, s1a, s2a, 256, 512);

  // ----- layer 2: agg(BN(h1)) -> GEMM2 (f16 permuted out + stats) -----
  k_agg16<true><<<dim3(NN/4,2),T,0,stream>>>(h1h, rowptr, csrc, ccf, dinv2,
                                             s1a, s2a, g1, be1, aggh, 512);
  k_w16<<<(512*1024)/T,T,0,stream>>>(W2, Wt, 512, 1024, 1024);
  k_gemm16<true><<<dim3(8,GR),T,0,stream>>>(aggh, Wt, nullptr, nullptr, h2h, s1b, s2b, 512, 1024);

  // ----- layer 3: agg(BN(h2)) -> GEMM3 (f32 out + b3) -----
  k_agg16<true><<<dim3(NN/4,4),T,0,stream>>>(h2h, rowptr, csrc, ccf, dinv2,
                                             s1b, s2b, g2, be2, aggh, 1024);
  k_w16<<<(1024*3072)/T,T,0,stream>>>(W3, Wt, 1024, 3000, 3072);
  k_gemm16<false><<<dim3(24,GR),T,0,stream>>>(aggh, Wt, b3, out, nullptr, nullptr, nullptr, 1024, 3000);
}

// Round 6
// 1804.008 us; speedup vs baseline: 6.9607x; 1.0834x over previous
//
#include <hip/hip_runtime.h>

#define NN 50000
#define NE 800000
#define EPSV 1e-5f

typedef _Float16 f16;
typedef __attribute__((ext_vector_type(4)))  float f32x4;
typedef __attribute__((ext_vector_type(16))) float f32x16;
typedef __attribute__((ext_vector_type(8)))  f16 f16x8;
typedef __attribute__((ext_vector_type(4)))  f16 f16x4;

// permuted k order within each 16-group: quads [0,2,1,3] so each MFMA fragment
// (lane-lo: {0-3,8-11}, lane-hi: {4-7,12-15}) is one contiguous 16B chunk.
// involution: kperm(kperm(k)) == k; preserves offset within a quad.
static __device__ __forceinline__ int kperm(int k){
  int q = (k>>2)&3;
  int p = ((q&1)<<1) | (q>>1);
  return (k & ~15) + (p<<2) + (k&3);
}

// ---------- degree / CSR build ----------
__global__ void k_init_deg(float* __restrict__ deg){
  int i = blockIdx.x*256 + threadIdx.x;
  if (i < NN) deg[i] = 1.0f;
}

__global__ void k_build(const int* __restrict__ ei, const float* __restrict__ ea,
                        int* __restrict__ cnt, float* __restrict__ deg){
  int e = blockIdx.x*256 + threadIdx.x;
  if (e < NE){
    int d = ei[NE + e];
    atomicAdd(&cnt[d], 1);
    atomicAdd(&deg[d], ea[3*e+2]);
  }
}

__global__ void k_fin_deg(const float* __restrict__ deg, float* __restrict__ dinv,
                          float* __restrict__ dinv2){
  int i = blockIdx.x*256 + threadIdx.x;
  if (i < NN){ float r = rsqrtf(deg[i]); dinv[i] = r; dinv2[i] = r*r; }
}

__global__ __launch_bounds__(1024) void k_scan(const int* __restrict__ cnt,
                                               int* __restrict__ rowptr,
                                               int* __restrict__ cursor){
  __shared__ int sums[1024];
  int t = threadIdx.x;
  int b0 = t*49, b1 = b0+49; if (b0 > NN) b0 = NN; if (b1 > NN) b1 = NN;
  int s = 0;
  for (int i = b0; i < b1; ++i) s += cnt[i];
  sums[t] = s; __syncthreads();
  for (int o = 1; o < 1024; o <<= 1){
    int v = (t >= o) ? sums[t-o] : 0;
    __syncthreads();
    sums[t] += v;
    __syncthreads();
  }
  int p = sums[t] - s;
  for (int i = b0; i < b1; ++i){ rowptr[i] = p; cursor[i] = p; p += cnt[i]; }
  if (t == 1023) rowptr[NN] = sums[1023];
}

__global__ void k_fill(const int* __restrict__ ei, const float* __restrict__ ea,
                       const float* __restrict__ dinv, int* __restrict__ cursor,
                       int* __restrict__ csrc, float* __restrict__ ccf){
  int e = blockIdx.x*256 + threadIdx.x;
  if (e < NE){
    int s = ei[e], d = ei[NE+e];
    float w = ea[3*e+2];
    int p = atomicAdd(&cursor[d], 1);
    csrc[p] = s;
    ccf[p] = dinv[s]*w*dinv[d];
  }
}

// ---------- x f32 -> fp16 (k-permuted) ----------
__global__ void k_xconv(const float* __restrict__ x, f16* __restrict__ xh){
  int idx = blockIdx.x*256 + threadIdx.x;      // quad index
  if (idx >= NN*64) return;
  int node = idx >> 6, k = (idx & 63)*4;
  f32x4 v = *(const f32x4*)(x + (size_t)node*256 + k);
  f16x4 h;
  #pragma unroll
  for (int j=0;j<4;++j) h[j] = (f16)v[j];
  *(f16x4*)(xh + (size_t)node*256 + kperm(k)) = h;
}

// ---------- W transpose -> fp16 [n][k] (k-permuted, n zero-padded) ----------
__global__ void k_w16(const float* __restrict__ W, f16* __restrict__ Wt,
                      int K, int M, int Mpad){
  int idx = blockIdx.x*256 + threadIdx.x;
  if (idx >= K*Mpad) return;
  int k = idx / Mpad, n = idx % Mpad;
  float v = (n < M) ? W[(size_t)k*M + n] : 0.f;
  Wt[(size_t)n*K + kperm(k)] = (f16)v;
}

// ---------- aggregation (CSR gather, f16x8 lanes), optional fused BN+ReLU ----------
// All f16 activations stored k-permuted. s1/s2 indexed by STORED col; g/be by
// ACTUAL col. K=256: 2 nodes per wave (half-wave each); K>=512: 1 node/wave,
// 512 cols per y-block.
template<int K, bool BN>
__global__ __launch_bounds__(256) void k_agg16(
    const f16* __restrict__ H, const int* __restrict__ rp,
    const int* __restrict__ cs, const float* __restrict__ cf,
    const float* __restrict__ dinv2,
    const float* __restrict__ s1, const float* __restrict__ s2,
    const float* __restrict__ g, const float* __restrict__ be,
    f16* __restrict__ outp)
{
  const int tid = threadIdx.x;
  int node, c;
  if (K == 256){
    node = blockIdx.x*8 + (tid>>5);
    c = (tid&31)*8;
  } else {
    node = blockIdx.x*4 + (tid>>6);
    c = (blockIdx.y<<9) + (tid&63)*8;
  }
  if (node >= NN) return;
  float av[8], bv[8];
  if (BN){
    int qa0 = kperm(c), qa1 = kperm(c+4);   // the two quads map separately
    #pragma unroll
    for (int j=0;j<8;++j){
      int ac = (j<4) ? qa0+j : qa1+(j-4);
      float mm = s1[c+j]*(1.f/NN);
      float var = s2[c+j]*(1.f/NN) - mm*mm;
      float sc = rsqrtf(var+EPSV)*g[ac];
      av[j] = sc;
      bv[j] = fmaf(-mm, sc, be[ac]);
    }
  }
  f16x8 hv = *(const f16x8*)(H + (size_t)node*K + c);
  float d2 = dinv2[node];
  float acc[8];
  #pragma unroll
  for (int j=0;j<8;++j){
    float v = (float)hv[j];
    if (BN){ v = fmaf(v, av[j], bv[j]); v = v > 0.f ? v : 0.f; }
    acc[j] = d2*v;
  }
  int e0 = rp[node], e1 = rp[node+1];
  for (int e = e0; e < e1; ++e){
    int s = cs[e]; float w = cf[e];
    f16x8 v8 = *(const f16x8*)(H + (size_t)s*K + c);
    #pragma unroll
    for (int j=0;j<8;++j){
      float v = (float)v8[j];
      if (BN){ v = fmaf(v, av[j], bv[j]); v = v > 0.f ? v : 0.f; }
      acc[j] += w*v;
    }
  }
  f16x8 o;
  #pragma unroll
  for (int j=0;j<8;++j) o[j] = (f16)acc[j];
  *(f16x8*)(outp + (size_t)node*K + c) = o;
}

// ---------- fp16 MFMA GEMM, 2-phase double-buffered (T3-min structure) ----------
// STATS=true: write f16 at k-PERMUTED column position (next GEMM's A layout),
//             accumulate per-stored-column sum/sumsq into s1/s2 (bias cancels).
// STATS=false: write f32 + bias at actual column position (final output).
template<bool STATS>
__global__ __launch_bounds__(256) void k_gemm16(
    const f16* __restrict__ A, const f16* __restrict__ B,
    const float* __restrict__ bias, float* __restrict__ Cf,
    f16* __restrict__ Ch, float* __restrict__ s1, float* __restrict__ s2,
    int K, int M)
{
  __shared__ f16 Ah[2][4096];
  __shared__ f16 Bh[2][4096];
  const int tid  = threadIdx.x;
  const int lane = tid & 63;
  const int wave = tid >> 6;
  const int wr = wave >> 1, wc = wave & 1;

  int nwg = gridDim.x*gridDim.y;
  int bid = blockIdx.y*gridDim.x + blockIdx.x;
  if ((nwg & 7) == 0){
    int cpx = nwg >> 3;
    bid = (bid & 7)*cpx + (bid >> 3);
  }
  const int bx = bid % gridDim.x, by = bid / gridDim.x;
  const int row0 = by*128, col0 = bx*128;

  f32x16 acc[2][2];
  #pragma unroll
  for (int m=0;m<2;++m)
    #pragma unroll
    for (int n=0;n<2;++n)
      #pragma unroll
      for (int t=0;t<16;++t) acc[m][n][t] = 0.f;

  // stage one 128x32 A-tile + B-tile into buffer `buf` (linear LDS, inverse
  // chunk-swizzle applied on the per-lane global source)
  auto stage = [&](int buf, int k0){
    #pragma unroll
    for (int i=0;i<2;++i){
      int phys = i*256 + tid;
      int rr = phys >> 2, cp = phys & 3;
      int sc2 = cp ^ ((rr>>1)&3);
      const f16* srcA = A + (size_t)(row0+rr)*K + k0 + sc2*8;
      const f16* srcB = B + (size_t)(col0+rr)*K + k0 + sc2*8;
      f16* dstA = &Ah[buf][(size_t)(i*256 + (wave<<6))*8];
      f16* dstB = &Bh[buf][(size_t)(i*256 + (wave<<6))*8];
      __builtin_amdgcn_global_load_lds((const unsigned int*)srcA, (unsigned int*)dstA, 16, 0, 0);
      __builtin_amdgcn_global_load_lds((const unsigned int*)srcB, (unsigned int*)dstB, 16, 0, 0);
    }
  };

  stage(0, 0);
  __syncthreads();                       // drain vmcnt, tile 0 ready
  const int nT = K >> 5;
  for (int t = 0; t < nT; ++t){
    const int cur = t & 1;
    if (t + 1 < nT) stage(cur^1, (t+1) << 5);   // prefetch next tile (overlaps MFMA)

    const int hg = lane >> 5;
    #pragma unroll
    for (int c2=0;c2<2;++c2){
      f16x8 fa[2], fb[2];
      #pragma unroll
      for (int m=0;m<2;++m){
        int r = wr*64 + m*32 + (lane&31);
        int u = c2*2 + hg;
        fa[m] = *(const f16x8*)&Ah[cur][r*32 + ((u ^ ((r>>1)&3))<<3)];
      }
      #pragma unroll
      for (int n=0;n<2;++n){
        int r = wc*64 + n*32 + (lane&31);
        int u = c2*2 + hg;
        fb[n] = *(const f16x8*)&Bh[cur][r*32 + ((u ^ ((r>>1)&3))<<3)];
      }
      #pragma unroll
      for (int m=0;m<2;++m)
        #pragma unroll
        for (int n=0;n<2;++n)
          acc[m][n] = __builtin_amdgcn_mfma_f32_32x32x16_f16(fa[m], fb[n], acc[m][n], 0,0,0);
    }
    __syncthreads();   // waits lgkmcnt(0) (our reads) + vmcnt(0) (next tile staged)
  }

  // epilogue: C/D 32x32 layout col=lane&31, row=(t&3)+8*((t>>2)&3)+4*(lane>>5)
  #pragma unroll
  for (int n=0;n<2;++n){
    int cg = col0 + wc*64 + n*32 + (lane&31);   // ACTUAL output column
    if (STATS){
      int cp = kperm(cg);                       // STORED (permuted) position
      float sum = 0.f, sq = 0.f;
      #pragma unroll
      for (int m=0;m<2;++m){
        #pragma unroll
        for (int t=0;t<16;++t){
          int rg = row0 + wr*64 + m*32 + (t&3) + ((t>>2)&3)*8 + ((lane>>5)<<2);
          if (rg < NN){
            float v = acc[m][n][t];
            sum += v; sq += v*v;
            Ch[(size_t)rg*M + cp] = (f16)v;
          }
        }
      }
      atomicAdd(&s1[cp], sum);
      atomicAdd(&s2[cp], sq);
    } else {
      float bv = (cg < M) ? bias[cg] : 0.f;
      #pragma unroll
      for (int m=0;m<2;++m){
        #pragma unroll
        for (int t=0;t<16;++t){
          int rg = row0 + wr*64 + m*32 + (t&3) + ((t>>2)&3)*8 + ((lane>>5)<<2);
          if (rg < NN && cg < M)
            Cf[(size_t)rg*M + cg] = acc[m][n][t] + bv;
        }
      }
    }
  }
}

extern "C" void kernel_launch(void* const* d_in, const int* in_sizes, int n_in,
                              void* d_out, int out_size, void* d_ws, size_t ws_size,
                              hipStream_t stream){
  const float* x   = (const float*)d_in[0];
  const int*   ei  = (const int*)d_in[1];
  const float* ea  = (const float*)d_in[2];
  const float* W1  = (const float*)d_in[4];
  const float* g1  = (const float*)d_in[6];
  const float* be1 = (const float*)d_in[7];
  const float* W2  = (const float*)d_in[8];
  const float* g2  = (const float*)d_in[10];
  const float* be2 = (const float*)d_in[11];
  const float* W3  = (const float*)d_in[12];
  const float* b3  = (const float*)d_in[13];
  float* out = (float*)d_out;

  // ---- workspace ----
  char* p = (char*)d_ws;
  int*   cnt    = (int*)p;   p += (size_t)NN*4;
  int*   cursor = (int*)p;   p += (size_t)NN*4;
  int*   rowptr = (int*)p;   p += (size_t)(NN+4)*4;
  float* deg    = (float*)p; p += (size_t)NN*4;
  float* dinv   = (float*)p; p += (size_t)NN*4;
  float* dinv2  = (float*)p; p += (size_t)NN*4;
  int*   csrc   = (int*)p;   p += (size_t)NE*4;
  float* ccf    = (float*)p; p += (size_t)NE*4;
  f16*   Wt     = (f16*)p;   p += (size_t)3072*1024*2;
  float* s1a    = (float*)p; p += 1024*4;   // layer-1 stats (512 used)
  float* s2a    = (float*)p; p += 1024*4;
  float* s1b    = (float*)p; p += 1024*4;   // layer-2 stats
  float* s2b    = (float*)p; p += 1024*4;
  f16*   aggh   = (f16*)p;   p += (size_t)50176*1024*2;  // padded rows

  // ---- stage in d_out (dead before final GEMM rewrites d_out) ----
  f16* xh  = (f16*)out;                    // NN*256 f16
  f16* h1h = xh  + (size_t)NN*256;         // NN*512 f16  (raw GEMM1 out, permuted)
  f16* h2h = h1h + (size_t)NN*512;         // NN*1024 f16 (raw GEMM2 out, permuted)

  const int T = 256;
  const int gN = (NN+T-1)/T, gE = NE/T;
  const int GR = (NN+127)/128;  // 391 row-blocks

  // graph prep
  hipMemsetAsync(cnt, 0, (size_t)NN*4, stream);
  hipMemsetAsync(s1a, 0, 4*1024*4, stream);   // zero all four stat buffers
  k_init_deg<<<gN,T,0,stream>>>(deg);
  k_build<<<gE,T,0,stream>>>(ei, ea, cnt, deg);
  k_fin_deg<<<gN,T,0,stream>>>(deg, dinv, dinv2);
  k_scan<<<1,1024,0,stream>>>(cnt, rowptr, cursor);
  k_fill<<<gE,T,0,stream>>>(ei, ea, dinv, cursor, csrc, ccf);
  k_xconv<<<(NN*64+T-1)/T,T,0,stream>>>(x, xh);

  // ----- layer 1: agg(x) -> GEMM1 (f16 permuted out + stats) -----
  k_agg16<256,false><<<dim3(NN/8,1),T,0,stream>>>(xh, rowptr, csrc, ccf, dinv2,
                                                  nullptr,nullptr,nullptr,nullptr, aggh);
  k_w16<<<(256*512)/T,T,0,stream>>>(W1, Wt, 256, 512, 512);
  k_gemm16<true><<<dim3(4,GR),T,0,stream>>>(aggh, Wt, nullptr, nullptr, h1h, s1a, s2a, 256, 512);

  // ----- layer 2: agg(BN(h1)) -> GEMM2 (f16 permuted out + stats) -----
  k_agg16<512,true><<<dim3(NN/4,1),T,0,stream>>>(h1h, rowptr, csrc, ccf, dinv2,
                                                 s1a, s2a, g1, be1, aggh);
  k_w16<<<(512*1024)/T,T,0,stream>>>(W2, Wt, 512, 1024, 1024);
  k_gemm16<true><<<dim3(8,GR),T,0,stream>>>(aggh, Wt, nullptr, nullptr, h2h, s1b, s2b, 512, 1024);

  // ----- layer 3: agg(BN(h2)) -> GEMM3 (f32 out + b3) -----
  k_agg16<1024,true><<<dim3(NN/4,2),T,0,stream>>>(h2h, rowptr, csrc, ccf, dinv2,
                                                  s1b, s2b, g2, be2, aggh);
  k_w16<<<(1024*3072)/T,T,0,stream>>>(W3, Wt, 1024, 3000, 3072);
  k_gemm16<false><<<dim3(24,GR),T,0,stream>>>(aggh, Wt, b3, out, nullptr, nullptr, nullptr, 1024, 3000);
}

// Round 7
// 1700.026 us; speedup vs baseline: 7.3865x; 1.0612x over previous
//
#include <hip/hip_runtime.h>

#define NN 50000
#define NE 800000
#define EPSV 1e-5f

typedef _Float16 f16;
typedef __attribute__((ext_vector_type(4)))  float f32x4;
typedef __attribute__((ext_vector_type(16))) float f32x16;
typedef __attribute__((ext_vector_type(8)))  f16 f16x8;
typedef __attribute__((ext_vector_type(4)))  f16 f16x4;

// permuted k order within each 16-group: quads [0,2,1,3] so each MFMA fragment
// (lane-lo: {0-3,8-11}, lane-hi: {4-7,12-15}) is one contiguous 16B chunk.
// involution: kperm(kperm(k)) == k; preserves offset within a quad.
static __device__ __forceinline__ int kperm(int k){
  int q = (k>>2)&3;
  int p = ((q&1)<<1) | (q>>1);
  return (k & ~15) + (p<<2) + (k&3);
}

// ---------- degree / CSR build ----------
__global__ void k_init_deg(float* __restrict__ deg){
  int i = blockIdx.x*256 + threadIdx.x;
  if (i < NN) deg[i] = 1.0f;
}

__global__ void k_build(const int* __restrict__ ei, const float* __restrict__ ea,
                        int* __restrict__ cnt, float* __restrict__ deg){
  int e = blockIdx.x*256 + threadIdx.x;
  if (e < NE){
    int d = ei[NE + e];
    atomicAdd(&cnt[d], 1);
    atomicAdd(&deg[d], ea[3*e+2]);
  }
}

__global__ void k_fin_deg(const float* __restrict__ deg, float* __restrict__ dinv,
                          float* __restrict__ dinv2){
  int i = blockIdx.x*256 + threadIdx.x;
  if (i < NN){ float r = rsqrtf(deg[i]); dinv[i] = r; dinv2[i] = r*r; }
}

__global__ __launch_bounds__(1024) void k_scan(const int* __restrict__ cnt,
                                               int* __restrict__ rowptr,
                                               int* __restrict__ cursor){
  __shared__ int sums[1024];
  int t = threadIdx.x;
  int b0 = t*49, b1 = b0+49; if (b0 > NN) b0 = NN; if (b1 > NN) b1 = NN;
  int s = 0;
  for (int i = b0; i < b1; ++i) s += cnt[i];
  sums[t] = s; __syncthreads();
  for (int o = 1; o < 1024; o <<= 1){
    int v = (t >= o) ? sums[t-o] : 0;
    __syncthreads();
    sums[t] += v;
    __syncthreads();
  }
  int p = sums[t] - s;
  for (int i = b0; i < b1; ++i){ rowptr[i] = p; cursor[i] = p; p += cnt[i]; }
  if (t == 1023) rowptr[NN] = sums[1023];
}

__global__ void k_fill(const int* __restrict__ ei, const float* __restrict__ ea,
                       const float* __restrict__ dinv, int* __restrict__ cursor,
                       int* __restrict__ csrc, float* __restrict__ ccf){
  int e = blockIdx.x*256 + threadIdx.x;
  if (e < NE){
    int s = ei[e], d = ei[NE+e];
    float w = ea[3*e+2];
    int p = atomicAdd(&cursor[d], 1);
    csrc[p] = s;
    ccf[p] = dinv[s]*w*dinv[d];
  }
}

// ---------- x f32 -> fp16 (k-permuted) ----------
__global__ void k_xconv(const float* __restrict__ x, f16* __restrict__ xh){
  int idx = blockIdx.x*256 + threadIdx.x;      // quad index
  if (idx >= NN*64) return;
  int node = idx >> 6, k = (idx & 63)*4;
  f32x4 v = *(const f32x4*)(x + (size_t)node*256 + k);
  f16x4 h;
  #pragma unroll
  for (int j=0;j<4;++j) h[j] = (f16)v[j];
  *(f16x4*)(xh + (size_t)node*256 + kperm(k)) = h;
}

// ---------- W transpose -> fp16 [n][k] (k-permuted, n zero-padded) ----------
__global__ void k_w16(const float* __restrict__ W, f16* __restrict__ Wt,
                      int K, int M, int Mpad){
  int idx = blockIdx.x*256 + threadIdx.x;
  if (idx >= K*Mpad) return;
  int k = idx / Mpad, n = idx % Mpad;
  float v = (n < M) ? W[(size_t)k*M + n] : 0.f;
  Wt[(size_t)n*K + kperm(k)] = (f16)v;
}

// ---------- aggregation (CSR gather, f16x8 lanes), optional fused BN+ReLU ----------
// All f16 activations stored k-permuted. s1/s2 indexed by STORED col; g/be by
// ACTUAL col. K=256: 2 nodes per wave (half-wave each); K>=512: 1 node/wave,
// 512 cols per y-block.
template<int K, bool BN>
__global__ __launch_bounds__(256) void k_agg16(
    const f16* __restrict__ H, const int* __restrict__ rp,
    const int* __restrict__ cs, const float* __restrict__ cf,
    const float* __restrict__ dinv2,
    const float* __restrict__ s1, const float* __restrict__ s2,
    const float* __restrict__ g, const float* __restrict__ be,
    f16* __restrict__ outp)
{
  const int tid = threadIdx.x;
  int node, c;
  if (K == 256){
    node = blockIdx.x*8 + (tid>>5);
    c = (tid&31)*8;
  } else {
    node = blockIdx.x*4 + (tid>>6);
    c = (blockIdx.y<<9) + (tid&63)*8;
  }
  if (node >= NN) return;
  float av[8], bv[8];
  if (BN){
    int qa0 = kperm(c), qa1 = kperm(c+4);   // the two quads map separately
    #pragma unroll
    for (int j=0;j<8;++j){
      int ac = (j<4) ? qa0+j : qa1+(j-4);
      float mm = s1[c+j]*(1.f/NN);
      float var = s2[c+j]*(1.f/NN) - mm*mm;
      float sc = rsqrtf(var+EPSV)*g[ac];
      av[j] = sc;
      bv[j] = fmaf(-mm, sc, be[ac]);
    }
  }
  f16x8 hv = *(const f16x8*)(H + (size_t)node*K + c);
  float d2 = dinv2[node];
  float acc[8];
  #pragma unroll
  for (int j=0;j<8;++j){
    float v = (float)hv[j];
    if (BN){ v = fmaf(v, av[j], bv[j]); v = v > 0.f ? v : 0.f; }
    acc[j] = d2*v;
  }
  int e0 = rp[node], e1 = rp[node+1];
  for (int e = e0; e < e1; ++e){
    int s = cs[e]; float w = cf[e];
    f16x8 v8 = *(const f16x8*)(H + (size_t)s*K + c);
    #pragma unroll
    for (int j=0;j<8;++j){
      float v = (float)v8[j];
      if (BN){ v = fmaf(v, av[j], bv[j]); v = v > 0.f ? v : 0.f; }
      acc[j] += w*v;
    }
  }
  f16x8 o;
  #pragma unroll
  for (int j=0;j<8;++j) o[j] = (f16)acc[j];
  *(f16x8*)(outp + (size_t)node*K + c) = o;
}

// ---------- fp16 MFMA GEMM, 2-phase double-buffered ----------
// STATS=true: write f16 at k-PERMUTED column position (next GEMM's A layout),
//             accumulate per-stored-column sum/sumsq into s1/s2 (bias cancels).
// STATS=false: write f32 + bias at actual column position (final output) with
//              NON-TEMPORAL stores — C (600 MB) is write-once, and letting it
//              allocate in L2/L3 evicts A/W (measured: 920 MB FETCH vs 106 MB
//              ideal at R6).
template<bool STATS>
__global__ __launch_bounds__(256) void k_gemm16(
    const f16* __restrict__ A, const f16* __restrict__ B,
    const float* __restrict__ bias, float* __restrict__ Cf,
    f16* __restrict__ Ch, float* __restrict__ s1, float* __restrict__ s2,
    int K, int M)
{
  __shared__ f16 Ah[2][4096];
  __shared__ f16 Bh[2][4096];
  const int tid  = threadIdx.x;
  const int lane = tid & 63;
  const int wave = tid >> 6;
  const int wr = wave >> 1, wc = wave & 1;

  int nwg = gridDim.x*gridDim.y;
  int bid = blockIdx.y*gridDim.x + blockIdx.x;
  if ((nwg & 7) == 0){
    int cpx = nwg >> 3;
    bid = (bid & 7)*cpx + (bid >> 3);
  }
  const int bx = bid % gridDim.x, by = bid / gridDim.x;
  const int row0 = by*128, col0 = bx*128;

  f32x16 acc[2][2];
  #pragma unroll
  for (int m=0;m<2;++m)
    #pragma unroll
    for (int n=0;n<2;++n)
      #pragma unroll
      for (int t=0;t<16;++t) acc[m][n][t] = 0.f;

  auto stage = [&](int buf, int k0){
    #pragma unroll
    for (int i=0;i<2;++i){
      int phys = i*256 + tid;
      int rr = phys >> 2, cp = phys & 3;
      int sc2 = cp ^ ((rr>>1)&3);
      const f16* srcA = A + (size_t)(row0+rr)*K + k0 + sc2*8;
      const f16* srcB = B + (size_t)(col0+rr)*K + k0 + sc2*8;
      f16* dstA = &Ah[buf][(size_t)(i*256 + (wave<<6))*8];
      f16* dstB = &Bh[buf][(size_t)(i*256 + (wave<<6))*8];
      __builtin_amdgcn_global_load_lds((const unsigned int*)srcA, (unsigned int*)dstA, 16, 0, 0);
      __builtin_amdgcn_global_load_lds((const unsigned int*)srcB, (unsigned int*)dstB, 16, 0, 0);
    }
  };

  stage(0, 0);
  __syncthreads();
  const int nT = K >> 5;
  for (int t = 0; t < nT; ++t){
    const int cur = t & 1;
    if (t + 1 < nT) stage(cur^1, (t+1) << 5);

    const int hg = lane >> 5;
    #pragma unroll
    for (int c2=0;c2<2;++c2){
      f16x8 fa[2], fb[2];
      #pragma unroll
      for (int m=0;m<2;++m){
        int r = wr*64 + m*32 + (lane&31);
        int u = c2*2 + hg;
        fa[m] = *(const f16x8*)&Ah[cur][r*32 + ((u ^ ((r>>1)&3))<<3)];
      }
      #pragma unroll
      for (int n=0;n<2;++n){
        int r = wc*64 + n*32 + (lane&31);
        int u = c2*2 + hg;
        fb[n] = *(const f16x8*)&Bh[cur][r*32 + ((u ^ ((r>>1)&3))<<3)];
      }
      #pragma unroll
      for (int m=0;m<2;++m)
        #pragma unroll
        for (int n=0;n<2;++n)
          acc[m][n] = __builtin_amdgcn_mfma_f32_32x32x16_f16(fa[m], fb[n], acc[m][n], 0,0,0);
    }
    __syncthreads();
  }

  // epilogue: C/D 32x32 layout col=lane&31, row=(t&3)+8*((t>>2)&3)+4*(lane>>5)
  #pragma unroll
  for (int n=0;n<2;++n){
    int cg = col0 + wc*64 + n*32 + (lane&31);   // ACTUAL output column
    if (STATS){
      int cp = kperm(cg);                       // STORED (permuted) position
      float sum = 0.f, sq = 0.f;
      #pragma unroll
      for (int m=0;m<2;++m){
        #pragma unroll
        for (int t=0;t<16;++t){
          int rg = row0 + wr*64 + m*32 + (t&3) + ((t>>2)&3)*8 + ((lane>>5)<<2);
          if (rg < NN){
            float v = acc[m][n][t];
            sum += v; sq += v*v;
            Ch[(size_t)rg*M + cp] = (f16)v;
          }
        }
      }
      atomicAdd(&s1[cp], sum);
      atomicAdd(&s2[cp], sq);
    } else {
      float bv = (cg < M) ? bias[cg] : 0.f;
      #pragma unroll
      for (int m=0;m<2;++m){
        #pragma unroll
        for (int t=0;t<16;++t){
          int rg = row0 + wr*64 + m*32 + (t&3) + ((t>>2)&3)*8 + ((lane>>5)<<2);
          if (rg < NN && cg < M)
            __builtin_nontemporal_store(acc[m][n][t] + bv, &Cf[(size_t)rg*M + cg]);
        }
      }
    }
  }
}

extern "C" void kernel_launch(void* const* d_in, const int* in_sizes, int n_in,
                              void* d_out, int out_size, void* d_ws, size_t ws_size,
                              hipStream_t stream){
  const float* x   = (const float*)d_in[0];
  const int*   ei  = (const int*)d_in[1];
  const float* ea  = (const float*)d_in[2];
  const float* W1  = (const float*)d_in[4];
  const float* g1  = (const float*)d_in[6];
  const float* be1 = (const float*)d_in[7];
  const float* W2  = (const float*)d_in[8];
  const float* g2  = (const float*)d_in[10];
  const float* be2 = (const float*)d_in[11];
  const float* W3  = (const float*)d_in[12];
  const float* b3  = (const float*)d_in[13];
  float* out = (float*)d_out;

  // ---- workspace ----
  char* p = (char*)d_ws;
  int*   cnt    = (int*)p;   p += (size_t)NN*4;
  int*   cursor = (int*)p;   p += (size_t)NN*4;
  int*   rowptr = (int*)p;   p += (size_t)(NN+4)*4;
  float* deg    = (float*)p; p += (size_t)NN*4;
  float* dinv   = (float*)p; p += (size_t)NN*4;
  float* dinv2  = (float*)p; p += (size_t)NN*4;
  int*   csrc   = (int*)p;   p += (size_t)NE*4;
  float* ccf    = (float*)p; p += (size_t)NE*4;
  f16*   Wt     = (f16*)p;   p += (size_t)3072*1024*2;
  float* s1a    = (float*)p; p += 1024*4;   // layer-1 stats (512 used)
  float* s2a    = (float*)p; p += 1024*4;
  float* s1b    = (float*)p; p += 1024*4;   // layer-2 stats
  float* s2b    = (float*)p; p += 1024*4;
  f16*   aggh   = (f16*)p;   p += (size_t)50176*1024*2;  // padded rows

  // ---- stage in d_out (dead before final GEMM rewrites d_out) ----
  f16* xh  = (f16*)out;                    // NN*256 f16
  f16* h1h = xh  + (size_t)NN*256;         // NN*512 f16  (raw GEMM1 out, permuted)
  f16* h2h = h1h + (size_t)NN*512;         // NN*1024 f16 (raw GEMM2 out, permuted)

  const int T = 256;
  const int gN = (NN+T-1)/T, gE = NE/T;
  const int GR = (NN+127)/128;  // 391 row-blocks

  // graph prep
  hipMemsetAsync(cnt, 0, (size_t)NN*4, stream);
  hipMemsetAsync(s1a, 0, 4*1024*4, stream);   // zero all four stat buffers
  k_init_deg<<<gN,T,0,stream>>>(deg);
  k_build<<<gE,T,0,stream>>>(ei, ea, cnt, deg);
  k_fin_deg<<<gN,T,0,stream>>>(deg, dinv, dinv2);
  k_scan<<<1,1024,0,stream>>>(cnt, rowptr, cursor);
  k_fill<<<gE,T,0,stream>>>(ei, ea, dinv, cursor, csrc, ccf);
  k_xconv<<<(NN*64+T-1)/T,T,0,stream>>>(x, xh);

  // ----- layer 1: agg(x) -> GEMM1 (f16 permuted out + stats) -----
  k_agg16<256,false><<<dim3(NN/8,1),T,0,stream>>>(xh, rowptr, csrc, ccf, dinv2,
                                                  nullptr,nullptr,nullptr,nullptr, aggh);
  k_w16<<<(256*512)/T,T,0,stream>>>(W1, Wt, 256, 512, 512);
  k_gemm16<true><<<dim3(4,GR),T,0,stream>>>(aggh, Wt, nullptr, nullptr, h1h, s1a, s2a, 256, 512);

  // ----- layer 2: agg(BN(h1)) -> GEMM2 (f16 permuted out + stats) -----
  k_agg16<512,true><<<dim3(NN/4,1),T,0,stream>>>(h1h, rowptr, csrc, ccf, dinv2,
                                                 s1a, s2a, g1, be1, aggh);
  k_w16<<<(512*1024)/T,T,0,stream>>>(W2, Wt, 512, 1024, 1024);
  k_gemm16<true><<<dim3(8,GR),T,0,stream>>>(aggh, Wt, nullptr, nullptr, h2h, s1b, s2b, 512, 1024);

  // ----- layer 3: agg(BN(h2)) -> GEMM3 (f32 out + b3, nt stores) -----
  k_agg16<1024,true><<<dim3(NN/4,2),T,0,stream>>>(h2h, rowptr, csrc, ccf, dinv2,
                                                  s1b, s2b, g2, be2, aggh);
  k_w16<<<(1024*3072)/T,T,0,stream>>>(W3, Wt, 1024, 3000, 3072);
  k_gemm16<false><<<dim3(24,GR),T,0,stream>>>(aggh, Wt, b3, out, nullptr, nullptr, nullptr, 1024, 3000);
}